// Round 19
// baseline (165.426 us; speedup 1.0000x reference)
//
#include <hip/hip_runtime.h>
#include <hip/hip_bf16.h>
#include <hip/hip_fp16.h>
#include <type_traits>

#define DIM 128
#define NEG_SLOPE 0.2f
#define LDSP 136     // padded LDS row stride (fp16) for W tile
#define CAP 64       // CSR capacity per node (Poisson(16): P(deg>64) ~ 1e-13)
#define NB 256       // dst buckets for CSR build
#define SUBCAP 32    // slots per (block,bucket) cell; Poisson(8), 8.8 sigma

typedef _Float16 half8 __attribute__((ext_vector_type(8)));
typedef float floatx4 __attribute__((ext_vector_type(4)));

// ---------------------------------------------------------------------------
// Bucket body (R18): LDS histogram ranks + deterministic per-(block,bucket)
// sub-arenas. No global atomics, no pre-zeroed global state.
// ---------------------------------------------------------------------------
__device__ __forceinline__ void bucket_body(int bb, const int* __restrict__ src,
                                            const int* __restrict__ dst,
                                            int* __restrict__ bcnt,
                                            int2* __restrict__ arena,
                                            int E, int npb, int nblk,
                                            int* lhist) {
    int tid = threadIdx.x;
    if (tid < NB) lhist[tid] = 0;
    __syncthreads();

    int base = bb * 2048;
    int dd[8], ss[8], rk[8], bk[8];
#pragma unroll
    for (int k = 0; k < 8; ++k) {
        int i = base + k * 256 + tid;
        if (i < E) {
            dd[k] = dst[i];
            ss[k] = src[i];
            bk[k] = dd[k] / npb;
            rk[k] = atomicAdd(&lhist[bk[k]], 1);   // LDS atomic
        } else {
            bk[k] = -1;
        }
    }
    __syncthreads();

    if (tid < NB) {
        int c = lhist[tid];
        bcnt[(size_t)tid * nblk + bb] = (c < SUBCAP) ? c : SUBCAP;
    }

#pragma unroll
    for (int k = 0; k < 8; ++k) {
        if (bk[k] >= 0 && rk[k] < SUBCAP) {
            arena[((size_t)bk[k] * nblk + bb) * SUBCAP + rk[k]] = make_int2(dd[k], ss[k]);
        }
    }
}

// ---------------------------------------------------------------------------
// MFMA GEMM body (R12/R18-proven) with inline W f32->fp16 transpose staging.
// ---------------------------------------------------------------------------
template <typename TIN>
__device__ __forceinline__ void gemm_body(int gb, const TIN* __restrict__ X,
                                          const float* __restrict__ W,
                                          __half* __restrict__ Hh,
                                          const float* __restrict__ a_src,
                                          const float* __restrict__ a_dst,
                                          float* __restrict__ alsrc,
                                          float* __restrict__ aldst, int n,
                                          _Float16* Ws) {
    int tid = threadIdx.x;
    int row0 = gb * 64;

    for (int e = tid; e < DIM * DIM; e += 256) {
        int k = e >> 7, c = e & 127;
        Ws[c * LDSP + k] = (_Float16)W[e];
    }

    int lane = tid & 63;
    int w = tid >> 6;
    int lo = lane & 15, hi = lane >> 4;

    int arow = row0 + w * 16 + lo;
    int ar = (arow < n) ? arow : (n - 1);
    half8 av[4];
#pragma unroll
    for (int t = 0; t < 4; ++t) {
        if constexpr (std::is_same<TIN, float>::value) {
            float4 v0 = *(const float4*)&X[(size_t)ar * DIM + t * 32 + hi * 8];
            float4 v1 = *(const float4*)&X[(size_t)ar * DIM + t * 32 + hi * 8 + 4];
            half8 h = {(_Float16)v0.x, (_Float16)v0.y, (_Float16)v0.z, (_Float16)v0.w,
                       (_Float16)v1.x, (_Float16)v1.y, (_Float16)v1.z, (_Float16)v1.w};
            av[t] = h;
        } else {
            av[t] = *(const half8*)&X[(size_t)ar * DIM + t * 32 + hi * 8];
        }
    }
    __syncthreads();

    floatx4 acc[8] = {};
#pragma unroll
    for (int t = 0; t < 4; ++t) {
#pragma unroll
        for (int f = 0; f < 8; ++f) {
            half8 bv = *(half8*)&Ws[(f * 16 + lo) * LDSP + t * 32 + hi * 8];
            acc[f] = __builtin_amdgcn_mfma_f32_16x16x32_f16(av[t], bv, acc[f], 0, 0, 0);
        }
    }

    float als[8], ald[8];
#pragma unroll
    for (int f = 0; f < 8; ++f) {
        als[f] = a_src[f * 16 + lo];
        ald[f] = a_dst[f * 16 + lo];
    }
#pragma unroll
    for (int r = 0; r < 4; ++r) {
        int grow = row0 + w * 16 + hi * 4 + r;
        float ps = 0.f, pd = 0.f;
#pragma unroll
        for (int f = 0; f < 8; ++f) {
            float v = acc[f][r];
            ps = fmaf(v, als[f], ps);
            pd = fmaf(v, ald[f], pd);
        }
#pragma unroll
        for (int o = 1; o <= 8; o <<= 1) {
            ps += __shfl_xor(ps, o);
            pd += __shfl_xor(pd, o);
        }
        if (grow < n) {
#pragma unroll
            for (int f = 0; f < 8; ++f)
                Hh[(size_t)grow * DIM + f * 16 + lo] = __float2half(acc[f][r]);
            if (lo == 0) { alsrc[grow] = ps; aldst[grow] = pd; }
        }
    }
}

// ---------------------------------------------------------------------------
// Fused: bucket blocks [0,nBucket) || layer-1 gemm blocks (independent work).
// ---------------------------------------------------------------------------
__global__ __launch_bounds__(256, 4) void fused_bucket_gemm1(
        const int* __restrict__ esrc, const int* __restrict__ edst,
        int* __restrict__ bcnt, int2* __restrict__ arena, int E, int npb,
        int nBucket,
        const float* __restrict__ X, const float* __restrict__ W1,
        __half* __restrict__ Hh, const float* __restrict__ a_src,
        const float* __restrict__ a_dst, float* __restrict__ alsrc,
        float* __restrict__ aldst, int n) {
    __shared__ _Float16 Ws[DIM * LDSP];
    __shared__ int lhist[NB];
    int b = blockIdx.x;
    if (b < nBucket)
        bucket_body(b, esrc, edst, bcnt, arena, E, npb, nBucket, lhist);
    else
        gemm_body<float>(b - nBucket, X, W1, Hh, a_src, a_dst, alsrc, aldst, n, Ws);
}

// ---------------------------------------------------------------------------
// CSR phase 2 (R18): one block per bucket; LDS-only per-node counters.
// ---------------------------------------------------------------------------
__global__ __launch_bounds__(512) void build_kernel(const int2* __restrict__ arena,
                                                    const int* __restrict__ bcnt,
                                                    int* __restrict__ cnt,
                                                    int* __restrict__ csr,
                                                    int n, int npb, int nblk) {
    __shared__ int lcnt[NB];   // npb <= 256
    int B = blockIdx.x;
    int tid = threadIdx.x;
    int dlo = B * npb;

    if (tid < npb) lcnt[tid] = 0;
    __syncthreads();

    for (int c = tid; c < nblk; c += 512) {
        int m = bcnt[(size_t)B * nblk + c];
        const int2* ap = &arena[((size_t)B * nblk + c) * SUBCAP];
        for (int i = 0; i < m; ++i) {
            int2 e = ap[i];
            int li = e.x - dlo;
            if (li >= 0 && li < npb) {
                int r = atomicAdd(&lcnt[li], 1);     // LDS atomic
                if (r < CAP) csr[(size_t)e.x * CAP + r] = e.y;
            }
        }
    }
    __syncthreads();

    if (tid < npb) {
        int d = dlo + tid;
        if (d < n) {
            int c = lcnt[tid];
            cnt[d] = (c < CAP) ? c : CAP;
        }
    }
}

// ---------------------------------------------------------------------------
// Layer-1 aggregation FUSED with the layer-2 GEMM (128x128 matvec on the
// VALU, hidden under gather stalls) + layer-2 logit epilogue.
// 512 threads = 8 waves/block, one node per wave. W2 staged fp16-packed in
// LDS (32 KB, lane-pair columns -> 2-way bank alias = free); y1 bounced
// through a 512 B per-wave LDS buffer for broadcast reads.
// ---------------------------------------------------------------------------
__global__ __launch_bounds__(512) void agg1_fused_kernel(
        const __half* __restrict__ Hh, const int* __restrict__ cnt,
        const int* __restrict__ csr, const float* __restrict__ alsrc,
        const float* __restrict__ aldst, const float* __restrict__ bias1,
        const float* __restrict__ W2, const float* __restrict__ asrc2,
        const float* __restrict__ adst2,
        __half* __restrict__ H2h, float* __restrict__ alsrc2,
        float* __restrict__ aldst2, int n) {
    __shared__ unsigned int w2p[DIM * 64];   // half2-packed W2 [k][c/2], 32 KB
    __shared__ float yb[8][DIM];             // per-wave y1 row, 4 KB

    int tid = threadIdx.x;
    // stage W2 f32 -> packed half2 (cols 2c,2c+1 per word)
    for (int e = tid * 2; e < DIM * DIM; e += 512 * 2) {
        float2 v = *(const float2*)&W2[e];
        __half2 h = __floats2half2_rn(v.x, v.y);
        w2p[e >> 1] = *(unsigned int*)&h;
    }
    __syncthreads();

    int wv = tid >> 6;
    int lane = tid & 63;
    int wid = blockIdx.x * 8 + wv;
    if (wid >= n) return;

    // ---- R16-proven agg body ----
    int deg = cnt[wid];
    deg = (deg < CAP) ? deg : CAP;
    float ald = aldst[wid];

    float e_self = alsrc[wid] + ald;
    e_self = (e_self >= 0.f) ? e_self : NEG_SLOPE * e_self;

    int sIdx = 0;
    float eL = -INFINITY;
    if (lane < deg) {
        sIdx = csr[(size_t)wid * CAP + lane];
        float e = alsrc[sIdx] + ald;
        eL = (e >= 0.f) ? e : NEG_SLOPE * e;
    }
    float m = fmaxf(e_self, eL);
#pragma unroll
    for (int o = 32; o > 0; o >>= 1) m = fmaxf(m, __shfl_xor(m, o));

    float wL = (lane < deg) ? __expf(eL - m) : 0.f;
    float dsum = wL;
#pragma unroll
    for (int o = 32; o > 0; o >>= 1) dsum += __shfl_xor(dsum, o);

    float wS = __expf(e_self - m);
    float denom = wS + dsum;

    int half = lane >> 5;
    int fl = (lane & 31) * 4;
    float a0 = 0.f, a1 = 0.f, a2 = 0.f, a3 = 0.f;
    int degP = (deg + 15) & ~15;

    for (int j = 0; j < degP; j += 16) {
        int s[8]; float w[8]; uint2 h[8];
#pragma unroll
        for (int q = 0; q < 8; ++q) {
            int idx = j + 2 * q + half;
            s[q] = __shfl(sIdx, idx);
            w[q] = __shfl(wL, idx);
        }
#pragma unroll
        for (int q = 0; q < 8; ++q)
            h[q] = *(const uint2*)&Hh[(size_t)s[q] * DIM + fl];
#pragma unroll
        for (int q = 0; q < 8; ++q) {
            float2 fa = __half22float2(*(__half2*)&h[q].x);
            float2 fb = __half22float2(*(__half2*)&h[q].y);
            a0 = fmaf(w[q], fa.x, a0);
            a1 = fmaf(w[q], fa.y, a1);
            a2 = fmaf(w[q], fb.x, a2);
            a3 = fmaf(w[q], fb.y, a3);
        }
    }

    a0 += __shfl_xor(a0, 32);
    a1 += __shfl_xor(a1, 32);
    a2 += __shfl_xor(a2, 32);
    a3 += __shfl_xor(a3, 32);

    // self-loop + bias1 + relu -> y1 row into per-wave LDS buffer
    if (half == 0) {
        uint2 hs = *(const uint2*)&Hh[(size_t)wid * DIM + fl];
        float2 ha = __half22float2(*(__half2*)&hs.x);
        float2 hb = __half22float2(*(__half2*)&hs.y);
        a0 = fmaf(wS, ha.x, a0);
        a1 = fmaf(wS, ha.y, a1);
        a2 = fmaf(wS, hb.x, a2);
        a3 = fmaf(wS, hb.y, a3);

        float inv = 1.0f / denom;
        float4 bv = *(const float4*)&bias1[fl];
        float y0 = fmaxf(fmaf(a0, inv, bv.x), 0.0f);
        float y1v = fmaxf(fmaf(a1, inv, bv.y), 0.0f);
        float y2 = fmaxf(fmaf(a2, inv, bv.z), 0.0f);
        float y3 = fmaxf(fmaf(a3, inv, bv.w), 0.0f);
        *(float4*)&yb[wv][fl] = make_float4(y0, y1v, y2, y3);
    }
    // same-wave LDS visibility: drain outstanding ds_writes
    asm volatile("s_waitcnt lgkmcnt(0)" ::: "memory");

    // ---- matvec h2 = y1 @ W2 (lane owns cols 2*lane, 2*lane+1) ----
    float h2a = 0.f, h2b = 0.f;
    for (int k4 = 0; k4 < 32; ++k4) {
        float ya[4];
        *(float4*)ya = *(float4*)&yb[wv][k4 * 4];
#pragma unroll
        for (int j = 0; j < 4; ++j) {
            unsigned int wp = w2p[(k4 * 4 + j) * 64 + lane];
            float2 wf = __half22float2(*(__half2*)&wp);
            h2a = fmaf(ya[j], wf.x, h2a);
            h2b = fmaf(ya[j], wf.y, h2b);
        }
    }

    // layer-2 attention logits from h2
    float ps = h2a * asrc2[2 * lane] + h2b * asrc2[2 * lane + 1];
    float pd = h2a * adst2[2 * lane] + h2b * adst2[2 * lane + 1];
#pragma unroll
    for (int o = 1; o <= 32; o <<= 1) {
        ps += __shfl_xor(ps, o);
        pd += __shfl_xor(pd, o);
    }
    if (lane == 0) { alsrc2[wid] = ps; aldst2[wid] = pd; }

    // store h2 (fp16), coalesced 256 B per wave
    __half2 hh = __floats2half2_rn(h2a, h2b);
    *(__half2*)&H2h[(size_t)wid * DIM + lane * 2] = hh;
}

// ---------------------------------------------------------------------------
// Layer-2 aggregation (R16-proven): one wave per dst node, pair-gather,
// uniform padded 16-edge batches, f32 output.
// ---------------------------------------------------------------------------
__global__ __launch_bounds__(256) void agg2_kernel(const __half* __restrict__ Hh,
                                                   const int* __restrict__ cnt,
                                                   const int* __restrict__ csr,
                                                   const float* __restrict__ alsrc,
                                                   const float* __restrict__ aldst,
                                                   const float* __restrict__ bias,
                                                   float* __restrict__ OUT, int n) {
    int wid = (blockIdx.x * 256 + threadIdx.x) >> 6;
    int lane = threadIdx.x & 63;
    if (wid >= n) return;

    int deg = cnt[wid];
    deg = (deg < CAP) ? deg : CAP;
    float ald = aldst[wid];

    float e_self = alsrc[wid] + ald;
    e_self = (e_self >= 0.f) ? e_self : NEG_SLOPE * e_self;

    int sIdx = 0;
    float eL = -INFINITY;
    if (lane < deg) {
        sIdx = csr[(size_t)wid * CAP + lane];
        float e = alsrc[sIdx] + ald;
        eL = (e >= 0.f) ? e : NEG_SLOPE * e;
    }
    float m = fmaxf(e_self, eL);
#pragma unroll
    for (int o = 32; o > 0; o >>= 1) m = fmaxf(m, __shfl_xor(m, o));

    float wL = (lane < deg) ? __expf(eL - m) : 0.f;
    float dsum = wL;
#pragma unroll
    for (int o = 32; o > 0; o >>= 1) dsum += __shfl_xor(dsum, o);

    float wS = __expf(e_self - m);
    float denom = wS + dsum;

    int half = lane >> 5;
    int fl = (lane & 31) * 4;
    float a0 = 0.f, a1 = 0.f, a2 = 0.f, a3 = 0.f;
    int degP = (deg + 15) & ~15;

    for (int j = 0; j < degP; j += 16) {
        int s[8]; float w[8]; uint2 h[8];
#pragma unroll
        for (int q = 0; q < 8; ++q) {
            int idx = j + 2 * q + half;
            s[q] = __shfl(sIdx, idx);
            w[q] = __shfl(wL, idx);
        }
#pragma unroll
        for (int q = 0; q < 8; ++q)
            h[q] = *(const uint2*)&Hh[(size_t)s[q] * DIM + fl];
#pragma unroll
        for (int q = 0; q < 8; ++q) {
            float2 fa = __half22float2(*(__half2*)&h[q].x);
            float2 fb = __half22float2(*(__half2*)&h[q].y);
            a0 = fmaf(w[q], fa.x, a0);
            a1 = fmaf(w[q], fa.y, a1);
            a2 = fmaf(w[q], fb.x, a2);
            a3 = fmaf(w[q], fb.y, a3);
        }
    }

    a0 += __shfl_xor(a0, 32);
    a1 += __shfl_xor(a1, 32);
    a2 += __shfl_xor(a2, 32);
    a3 += __shfl_xor(a3, 32);

    if (half == 0) {
        uint2 hs = *(const uint2*)&Hh[(size_t)wid * DIM + fl];
        float2 ha = __half22float2(*(__half2*)&hs.x);
        float2 hb = __half22float2(*(__half2*)&hs.y);
        a0 = fmaf(wS, ha.x, a0);
        a1 = fmaf(wS, ha.y, a1);
        a2 = fmaf(wS, hb.x, a2);
        a3 = fmaf(wS, hb.y, a3);

        float inv = 1.0f / denom;
        float4 bv = *(const float4*)&bias[fl];
        float o0 = fmaxf(fmaf(a0, inv, bv.x), 0.0f);
        float o1 = fmaxf(fmaf(a1, inv, bv.y), 0.0f);
        float o2 = fmaxf(fmaf(a2, inv, bv.z), 0.0f);
        float o3 = fmaxf(fmaf(a3, inv, bv.w), 0.0f);
        *(float4*)&OUT[(size_t)wid * DIM + fl] = make_float4(o0, o1, o2, o3);
    }
}

// ---------------------------------------------------------------------------
extern "C" void kernel_launch(void* const* d_in, const int* in_sizes, int n_in,
                              void* d_out, int out_size, void* d_ws, size_t ws_size,
                              hipStream_t stream) {
    const float* x      = (const float*)d_in[0];
    const int*   eidx   = (const int*)d_in[1];
    const float* W1     = (const float*)d_in[3];
    const float* asrc1  = (const float*)d_in[4];
    const float* adst1  = (const float*)d_in[5];
    const float* b1     = (const float*)d_in[6];
    const float* W2     = (const float*)d_in[7];
    const float* asrc2  = (const float*)d_in[8];
    const float* adst2  = (const float*)d_in[9];
    const float* b2     = (const float*)d_in[10];
    float* out = (float*)d_out;

    int n = in_sizes[0] / DIM;        // 50000
    int E = in_sizes[1] / 2;          // 800000
    const int* esrc = eidx;
    const int* edst = eidx + E;

    int npb = (n + NB - 1) / NB;      // nodes per bucket (196)
    int nBucket = (E + 2047) / 2048;  // 391 bucket blocks

    // workspace layout
    __half* Hh     = (__half*)d_ws;                        // n*128 fp16 (layer-1 h)
    __half* H2h    = Hh + (size_t)n * DIM;                 // n*128 fp16 (layer-2 h)
    float* alsrc   = (float*)(H2h + (size_t)n * DIM);      // n
    float* aldst   = alsrc + n;                            // n
    float* alsrc2  = aldst + n;                            // n
    float* aldst2  = alsrc2 + n;                           // n
    int*   cnt     = (int*)(aldst2 + n);                   // n
    int*   csr     = cnt + n;                              // n*CAP
    int*   bcnt    = csr + (size_t)n * CAP;                // NB*nBucket
    int2*  arena   = (int2*)(bcnt + (size_t)NB * nBucket); // NB*nBucket*SUBCAP

    int gemm_grid = (n + 63) / 64;
    int wave_grid = (n + 3) / 4;

    // ---- fused: bucket (CSR phase 1, atomic-free) || layer-1 GEMM ----
    fused_bucket_gemm1<<<nBucket + gemm_grid, 256, 0, stream>>>(
        esrc, edst, bcnt, arena, E, npb, nBucket,
        x, W1, Hh, asrc1, adst1, alsrc, aldst, n);

    // ---- CSR phase 2 ----
    build_kernel<<<NB, 512, 0, stream>>>(arena, bcnt, cnt, csr, n, npb, nBucket);

    // ---- layer-1 aggregation + layer-2 GEMM (fused) ----
    agg1_fused_kernel<<<(n + 7) / 8, 512, 0, stream>>>(
        Hh, cnt, csr, alsrc, aldst, b1, W2, asrc2, adst2,
        H2h, alsrc2, aldst2, n);

    // ---- layer-2 aggregation ----
    agg2_kernel<<<wave_grid, 256, 0, stream>>>(H2h, cnt, csr, alsrc2, aldst2, b2, out, n);
}

// Round 20
// 123.745 us; speedup vs baseline: 1.3368x; 1.3368x over previous
//
#include <hip/hip_runtime.h>
#include <hip/hip_bf16.h>
#include <hip/hip_fp16.h>
#include <type_traits>

#define DIM 128
#define NEG_SLOPE 0.2f
#define LDSP 136     // padded LDS row stride (fp16) for W tile
#define CAP 64       // CSR capacity per node (Poisson(16): P(deg>64) ~ 1e-13)
#define NB 256       // dst buckets for CSR build
#define SUBCAP 32    // slots per (block,bucket) cell; Poisson(8), 8.8 sigma

typedef _Float16 half8 __attribute__((ext_vector_type(8)));
typedef float floatx4 __attribute__((ext_vector_type(4)));

// ---------------------------------------------------------------------------
// Bucket body (R18-proven): LDS histogram ranks + deterministic
// per-(block,bucket) sub-arenas. No global atomics, no pre-zeroed state.
// ---------------------------------------------------------------------------
__device__ __forceinline__ void bucket_body(int bb, const int* __restrict__ src,
                                            const int* __restrict__ dst,
                                            int* __restrict__ bcnt,
                                            int2* __restrict__ arena,
                                            int E, int npb, int nblk,
                                            int* lhist) {
    int tid = threadIdx.x;
    if (tid < NB) lhist[tid] = 0;
    __syncthreads();

    int base = bb * 2048;
    int dd[8], ss[8], rk[8], bk[8];
#pragma unroll
    for (int k = 0; k < 8; ++k) {
        int i = base + k * 256 + tid;
        if (i < E) {
            dd[k] = dst[i];
            ss[k] = src[i];
            bk[k] = dd[k] / npb;
            rk[k] = atomicAdd(&lhist[bk[k]], 1);   // LDS atomic
        } else {
            bk[k] = -1;
        }
    }
    __syncthreads();

    if (tid < NB) {
        int c = lhist[tid];
        bcnt[(size_t)tid * nblk + bb] = (c < SUBCAP) ? c : SUBCAP;
    }

#pragma unroll
    for (int k = 0; k < 8; ++k) {
        if (bk[k] >= 0 && rk[k] < SUBCAP) {
            arena[((size_t)bk[k] * nblk + bb) * SUBCAP + rk[k]] = make_int2(dd[k], ss[k]);
        }
    }
}

// ---------------------------------------------------------------------------
// MFMA GEMM body (R12/R18-proven) with inline W f32->fp16 transpose staging.
// ---------------------------------------------------------------------------
template <typename TIN>
__device__ __forceinline__ void gemm_body(int gb, const TIN* __restrict__ X,
                                          const float* __restrict__ W,
                                          __half* __restrict__ Hh,
                                          const float* __restrict__ a_src,
                                          const float* __restrict__ a_dst,
                                          float* __restrict__ alsrc,
                                          float* __restrict__ aldst, int n,
                                          _Float16* Ws) {
    int tid = threadIdx.x;
    int row0 = gb * 64;

    for (int e = tid; e < DIM * DIM; e += 256) {
        int k = e >> 7, c = e & 127;
        Ws[c * LDSP + k] = (_Float16)W[e];
    }

    int lane = tid & 63;
    int w = tid >> 6;
    int lo = lane & 15, hi = lane >> 4;

    int arow = row0 + w * 16 + lo;
    int ar = (arow < n) ? arow : (n - 1);
    half8 av[4];
#pragma unroll
    for (int t = 0; t < 4; ++t) {
        if constexpr (std::is_same<TIN, float>::value) {
            float4 v0 = *(const float4*)&X[(size_t)ar * DIM + t * 32 + hi * 8];
            float4 v1 = *(const float4*)&X[(size_t)ar * DIM + t * 32 + hi * 8 + 4];
            half8 h = {(_Float16)v0.x, (_Float16)v0.y, (_Float16)v0.z, (_Float16)v0.w,
                       (_Float16)v1.x, (_Float16)v1.y, (_Float16)v1.z, (_Float16)v1.w};
            av[t] = h;
        } else {
            av[t] = *(const half8*)&X[(size_t)ar * DIM + t * 32 + hi * 8];
        }
    }
    __syncthreads();

    floatx4 acc[8] = {};
#pragma unroll
    for (int t = 0; t < 4; ++t) {
#pragma unroll
        for (int f = 0; f < 8; ++f) {
            half8 bv = *(half8*)&Ws[(f * 16 + lo) * LDSP + t * 32 + hi * 8];
            acc[f] = __builtin_amdgcn_mfma_f32_16x16x32_f16(av[t], bv, acc[f], 0, 0, 0);
        }
    }

    float als[8], ald[8];
#pragma unroll
    for (int f = 0; f < 8; ++f) {
        als[f] = a_src[f * 16 + lo];
        ald[f] = a_dst[f * 16 + lo];
    }
#pragma unroll
    for (int r = 0; r < 4; ++r) {
        int grow = row0 + w * 16 + hi * 4 + r;
        float ps = 0.f, pd = 0.f;
#pragma unroll
        for (int f = 0; f < 8; ++f) {
            float v = acc[f][r];
            ps = fmaf(v, als[f], ps);
            pd = fmaf(v, ald[f], pd);
        }
#pragma unroll
        for (int o = 1; o <= 8; o <<= 1) {
            ps += __shfl_xor(ps, o);
            pd += __shfl_xor(pd, o);
        }
        if (grow < n) {
#pragma unroll
            for (int f = 0; f < 8; ++f)
                Hh[(size_t)grow * DIM + f * 16 + lo] = __float2half(acc[f][r]);
            if (lo == 0) { alsrc[grow] = ps; aldst[grow] = pd; }
        }
    }
}

// ---------------------------------------------------------------------------
// Fused: bucket blocks [0,nBucket) || layer-1 gemm blocks (independent work).
// ---------------------------------------------------------------------------
__global__ __launch_bounds__(256, 4) void fused_bucket_gemm1(
        const int* __restrict__ esrc, const int* __restrict__ edst,
        int* __restrict__ bcnt, int2* __restrict__ arena, int E, int npb,
        int nBucket,
        const float* __restrict__ X, const float* __restrict__ W1,
        __half* __restrict__ Hh, const float* __restrict__ a_src,
        const float* __restrict__ a_dst, float* __restrict__ alsrc,
        float* __restrict__ aldst, int n) {
    __shared__ _Float16 Ws[DIM * LDSP];
    __shared__ int lhist[NB];
    int b = blockIdx.x;
    if (b < nBucket)
        bucket_body(b, esrc, edst, bcnt, arena, E, npb, nBucket, lhist);
    else
        gemm_body<float>(b - nBucket, X, W1, Hh, a_src, a_dst, alsrc, aldst, n, Ws);
}

// ---------------------------------------------------------------------------
// Standalone gemm (layer 2).
// ---------------------------------------------------------------------------
__global__ __launch_bounds__(256, 4) void gemm2_kernel(const _Float16* __restrict__ X,
                                                       const float* __restrict__ W2,
                                                       __half* __restrict__ Hh,
                                                       const float* __restrict__ a_src,
                                                       const float* __restrict__ a_dst,
                                                       float* __restrict__ alsrc,
                                                       float* __restrict__ aldst, int n) {
    __shared__ _Float16 Ws[DIM * LDSP];
    gemm_body<_Float16>(blockIdx.x, X, W2, Hh, a_src, a_dst, alsrc, aldst, n, Ws);
}

// ---------------------------------------------------------------------------
// CSR phase 2 (R18-proven): one block per bucket; LDS-only per-node counters.
// ---------------------------------------------------------------------------
__global__ __launch_bounds__(512) void build_kernel(const int2* __restrict__ arena,
                                                    const int* __restrict__ bcnt,
                                                    int* __restrict__ cnt,
                                                    int* __restrict__ csr,
                                                    int n, int npb, int nblk) {
    __shared__ int lcnt[NB];   // npb <= 256
    int B = blockIdx.x;
    int tid = threadIdx.x;
    int dlo = B * npb;

    if (tid < npb) lcnt[tid] = 0;
    __syncthreads();

    for (int c = tid; c < nblk; c += 512) {
        int m = bcnt[(size_t)B * nblk + c];
        const int2* ap = &arena[((size_t)B * nblk + c) * SUBCAP];
        for (int i = 0; i < m; ++i) {
            int2 e = ap[i];
            int li = e.x - dlo;
            if (li >= 0 && li < npb) {
                int r = atomicAdd(&lcnt[li], 1);     // LDS atomic
                if (r < CAP) csr[(size_t)e.x * CAP + r] = e.y;
            }
        }
    }
    __syncthreads();

    if (tid < npb) {
        int d = dlo + tid;
        if (d < n) {
            int c = lcnt[tid];
            cnt[d] = (c < CAP) ? c : CAP;
        }
    }
}

// ---------------------------------------------------------------------------
// Aggregation (R16-proven): one wave per dst node, pair-gather, uniform
// padded 16-edge batches.
// ---------------------------------------------------------------------------
template <bool OUT16>
__global__ __launch_bounds__(256) void agg_kernel(const __half* __restrict__ Hh,
                                                  const int* __restrict__ cnt,
                                                  const int* __restrict__ csr,
                                                  const float* __restrict__ alsrc,
                                                  const float* __restrict__ aldst,
                                                  const float* __restrict__ bias,
                                                  void* __restrict__ OUTp, int n) {
    int wid = (blockIdx.x * 256 + threadIdx.x) >> 6;
    int lane = threadIdx.x & 63;
    if (wid >= n) return;

    int deg = cnt[wid];
    deg = (deg < CAP) ? deg : CAP;
    float ald = aldst[wid];

    float e_self = alsrc[wid] + ald;
    e_self = (e_self >= 0.f) ? e_self : NEG_SLOPE * e_self;

    int sIdx = 0;
    float eL = -INFINITY;
    if (lane < deg) {
        sIdx = csr[(size_t)wid * CAP + lane];          // coalesced
        float e = alsrc[sIdx] + ald;
        eL = (e >= 0.f) ? e : NEG_SLOPE * e;
    }
    float m = fmaxf(e_self, eL);
#pragma unroll
    for (int o = 32; o > 0; o >>= 1) m = fmaxf(m, __shfl_xor(m, o));

    float wL = (lane < deg) ? __expf(eL - m) : 0.f;
    float dsum = wL;
#pragma unroll
    for (int o = 32; o > 0; o >>= 1) dsum += __shfl_xor(dsum, o);

    float wS = __expf(e_self - m);
    float denom = wS + dsum;

    int half = lane >> 5;             // 0: even row of pair, 1: odd row
    int fl = (lane & 31) * 4;         // this lane's 4 feature dims
    float a0 = 0.f, a1 = 0.f, a2 = 0.f, a3 = 0.f;
    int degP = (deg + 15) & ~15;      // multiple of 16 (zero-weight padding)

    for (int j = 0; j < degP; j += 16) {
        int s[8]; float w[8]; uint2 h[8];
#pragma unroll
        for (int q = 0; q < 8; ++q) {
            int idx = j + 2 * q + half;
            s[q] = __shfl(sIdx, idx);
            w[q] = __shfl(wL, idx);
        }
#pragma unroll
        for (int q = 0; q < 8; ++q)
            h[q] = *(const uint2*)&Hh[(size_t)s[q] * DIM + fl];
#pragma unroll
        for (int q = 0; q < 8; ++q) {
            float2 fa = __half22float2(*(__half2*)&h[q].x);
            float2 fb = __half22float2(*(__half2*)&h[q].y);
            a0 = fmaf(w[q], fa.x, a0);
            a1 = fmaf(w[q], fa.y, a1);
            a2 = fmaf(w[q], fb.x, a2);
            a3 = fmaf(w[q], fb.y, a3);
        }
    }

    a0 += __shfl_xor(a0, 32);
    a1 += __shfl_xor(a1, 32);
    a2 += __shfl_xor(a2, 32);
    a3 += __shfl_xor(a3, 32);

    if (half == 0) {
        uint2 hs = *(const uint2*)&Hh[(size_t)wid * DIM + fl];
        float2 ha = __half22float2(*(__half2*)&hs.x);
        float2 hb = __half22float2(*(__half2*)&hs.y);
        a0 = fmaf(wS, ha.x, a0);
        a1 = fmaf(wS, ha.y, a1);
        a2 = fmaf(wS, hb.x, a2);
        a3 = fmaf(wS, hb.y, a3);

        float inv = 1.0f / denom;
        float4 bv = *(const float4*)&bias[fl];
        float o0 = fmaxf(fmaf(a0, inv, bv.x), 0.0f);
        float o1 = fmaxf(fmaf(a1, inv, bv.y), 0.0f);
        float o2 = fmaxf(fmaf(a2, inv, bv.z), 0.0f);
        float o3 = fmaxf(fmaf(a3, inv, bv.w), 0.0f);
        if constexpr (OUT16) {
            __half2 p0 = __floats2half2_rn(o0, o1);
            __half2 p1 = __floats2half2_rn(o2, o3);
            uint2 u;
            u.x = *(unsigned int*)&p0;
            u.y = *(unsigned int*)&p1;
            *(uint2*)&((__half*)OUTp)[(size_t)wid * DIM + fl] = u;
        } else {
            *(float4*)&((float*)OUTp)[(size_t)wid * DIM + fl] = make_float4(o0, o1, o2, o3);
        }
    }
}

// ---------------------------------------------------------------------------
extern "C" void kernel_launch(void* const* d_in, const int* in_sizes, int n_in,
                              void* d_out, int out_size, void* d_ws, size_t ws_size,
                              hipStream_t stream) {
    const float* x      = (const float*)d_in[0];
    const int*   eidx   = (const int*)d_in[1];
    const float* W1     = (const float*)d_in[3];
    const float* asrc1  = (const float*)d_in[4];
    const float* adst1  = (const float*)d_in[5];
    const float* b1     = (const float*)d_in[6];
    const float* W2     = (const float*)d_in[7];
    const float* asrc2  = (const float*)d_in[8];
    const float* adst2  = (const float*)d_in[9];
    const float* b2     = (const float*)d_in[10];
    float* out = (float*)d_out;

    int n = in_sizes[0] / DIM;        // 50000
    int E = in_sizes[1] / 2;          // 800000
    const int* esrc = eidx;
    const int* edst = eidx + E;

    int npb = (n + NB - 1) / NB;      // nodes per bucket (196)
    int nBucket = (E + 2047) / 2048;  // 391 bucket blocks

    // workspace layout
    __half* Hh     = (__half*)d_ws;                        // n*128 fp16
    __half* y1h    = Hh + (size_t)n * DIM;                 // n*128 fp16
    float* alsrc   = (float*)(y1h + (size_t)n * DIM);      // n
    float* aldst   = alsrc + n;                            // n
    int*   cnt     = (int*)(aldst + n);                    // n
    int*   csr     = cnt + n;                              // n*CAP
    int*   bcnt    = csr + (size_t)n * CAP;                // NB*nBucket
    int2*  arena   = (int2*)(bcnt + (size_t)NB * nBucket); // NB*nBucket*SUBCAP

    int gemm_grid = (n + 63) / 64;
    int wave_grid = (n + 3) / 4;

    // ---- fused: bucket (CSR phase 1, atomic-free) || layer-1 GEMM ----
    fused_bucket_gemm1<<<nBucket + gemm_grid, 256, 0, stream>>>(
        esrc, edst, bcnt, arena, E, npb, nBucket,
        x, W1, Hh, asrc1, adst1, alsrc, aldst, n);

    // ---- CSR phase 2 ----
    build_kernel<<<NB, 512, 0, stream>>>(arena, bcnt, cnt, csr, n, npb, nBucket);

    // ---- layer 1 aggregation ----
    agg_kernel<true><<<wave_grid, 256, 0, stream>>>(Hh, cnt, csr, alsrc, aldst, b1, y1h, n);

    // ---- layer 2 ----
    gemm2_kernel<<<gemm_grid, 256, 0, stream>>>((const _Float16*)y1h, W2, Hh, asrc2, adst2, alsrc, aldst, n);
    agg_kernel<false><<<wave_grid, 256, 0, stream>>>(Hh, cnt, csr, alsrc, aldst, b2, out, n);
}